// Round 2
// baseline (10.510 us; speedup 1.0000x reference)
//
#include <hip/hip_runtime.h>
#include <hip/hip_bf16.h>

// SWAP gate on qubits (0,1) of a 13-qubit state, batched B=256.
// U = kron(SWAP, I_2048)  =>  out[b][i] = in[b][ swap_bits_11_12(i) ]
// (bit pattern of i>>11: 00->00, 01->10, 10->01, 11->11).
// Pure permutation copy; U (d_in[1], 256 MiB) is never read.
//
// Round-1 journal: identical logic passed the initial exact check
// (absmax 0.0) but failed post-timing revalidation with no in-kernel
// mechanism (pure function of d_in[0], full d_out overwrite, no
// aliasing possible given the harness's pre-launch memset-0 passed).
// This round is a reproduce-test with grid derived from out_size.

#define DIM 8192          // 2^13
#define DIM_MASK (DIM - 1)

__global__ __launch_bounds__(256) void swap01_permute_kernel(
    const float4* __restrict__ in, float4* __restrict__ out, unsigned n4) {
    unsigned idx = blockIdx.x * blockDim.x + threadIdx.x;   // float4 index
    if (idx >= n4) return;

    unsigned fi   = idx << 2;                  // flat float index
    unsigned d    = fi & DIM_MASK;             // 13-bit dim index
    unsigned low  = d & 2047u;                 // low 11 bits (unchanged)
    unsigned top  = d >> 11;                   // top 2 bits
    unsigned swp  = ((top & 1u) << 1) | (top >> 1);
    unsigned src  = (fi & ~(unsigned)DIM_MASK) | (swp << 11) | low;

    out[idx] = in[src >> 2];
}

extern "C" void kernel_launch(void* const* d_in, const int* in_sizes, int n_in,
                              void* d_out, int out_size, void* d_ws, size_t ws_size,
                              hipStream_t stream) {
    const float4* in  = (const float4*)d_in[0];   // inputs [B, DIM, 1] fp32
    float4*       out = (float4*)d_out;           // [B, DIM, 1] fp32
    // d_in[1] is U [DIM, DIM] — fixed known permutation, never read.

    unsigned n4 = (unsigned)out_size >> 2;        // 524,288 float4
    dim3 block(256);
    dim3 grid((n4 + 255u) / 256u);                // 2048 blocks
    swap01_permute_kernel<<<grid, block, 0, stream>>>(in, out, n4);
}

// Round 3
// 10.491 us; speedup vs baseline: 1.0018x; 1.0018x over previous
//
#include <hip/hip_runtime.h>
#include <hip/hip_bf16.h>

// SWAP gate on qubits (0,1) of a 13-qubit state, batched B=256.
// U = kron(SWAP, I_2048)  =>  out[b][i] = in[b][ swap_bits_11_12(i) ]
// Pure permutation copy; U (d_in[1], 256 MiB) is never read.
//
// Round-2 journal: PASS, absmax 0.0, dur 10.51 us. Ideal mem time 2.7 us
// (16 MiB @ 6.3 TB/s) -> measured time sits at the ~10 us launch-overhead
// floor. This round: A/B confirm — 32 B/thread (2x float4, independent
// loads for ILP), 1024 blocks. Prediction: unchanged => overhead-bound,
// declare roofline.

#define DIM 8192          // 2^13
#define DIM_MASK (DIM - 1)

__device__ __forceinline__ unsigned swap_src_f4(unsigned idx4) {
    unsigned fi  = idx4 << 2;                 // flat float index
    unsigned d   = fi & DIM_MASK;             // 13-bit dim index
    unsigned low = d & 2047u;                 // low 11 bits (unchanged)
    unsigned top = d >> 11;                   // top 2 bits
    unsigned swp = ((top & 1u) << 1) | (top >> 1);
    unsigned src = (fi & ~(unsigned)DIM_MASK) | (swp << 11) | low;
    return src >> 2;                          // float4 index
}

__global__ __launch_bounds__(256) void swap01_permute_kernel(
    const float4* __restrict__ in, float4* __restrict__ out, unsigned n4) {
    // Each thread moves two float4 (32 B), independent loads for ILP.
    // Layout: thread t of block b handles float4 indices
    //   base + tid  and  base + tid + 256   (both fully coalesced).
    unsigned base = blockIdx.x * 512u + threadIdx.x;
    unsigned i0 = base;
    unsigned i1 = base + 256u;

    float4 v0, v1;
    bool ok0 = (i0 < n4), ok1 = (i1 < n4);
    if (ok0) v0 = in[swap_src_f4(i0)];
    if (ok1) v1 = in[swap_src_f4(i1)];
    if (ok0) out[i0] = v0;
    if (ok1) out[i1] = v1;
}

extern "C" void kernel_launch(void* const* d_in, const int* in_sizes, int n_in,
                              void* d_out, int out_size, void* d_ws, size_t ws_size,
                              hipStream_t stream) {
    const float4* in  = (const float4*)d_in[0];   // inputs [B, DIM, 1] fp32
    float4*       out = (float4*)d_out;           // [B, DIM, 1] fp32
    // d_in[1] is U [DIM, DIM] — fixed known permutation, never read.

    unsigned n4 = (unsigned)out_size >> 2;        // 524,288 float4
    dim3 block(256);
    dim3 grid((n4 + 511u) / 512u);                // 1024 blocks
    swap01_permute_kernel<<<grid, block, 0, stream>>>(in, out, n4);
}